// Round 4
// baseline (567.882 us; speedup 1.0000x reference)
//
#include <hip/hip_runtime.h>
#include <stdint.h>

#define H 1024
#define W 1024
#define HW (H * W)
#define TOPK 4096
#define NBINS 16384
#define CAND_CAP 65536
#define COMPACT_CAP 8192

// ---------------- ws layout (bytes) ----------------
// [0]      u32 cand_count
// [4]      u32 compact_count
// [8]      u32 b_star
// [12]     u32 m_count (info)
// [256,    256+NBINS*4)          hist            (64 KB)
// [65792,  65792+CAND_CAP*8)     candidate keys  (512 KB)
// [590080, 590080+COMPACT_CAP*8) compact keys    (64 KB)
// [655616, 655616+TOPK*4)        sorted idx      (16 KB)
#define OFF_HIST    256
#define OFF_KEYS    65792
#define OFF_COMPACT 590080
#define OFF_SIDX    655616

// K1: 5x5 NMS via LDS tile, append unique 64-bit key + histogram score bin.
// key = (score_bits << 32) | (0xFFFFFFFF - idx): larger key == higher score,
// ties -> smaller flat index (matches lax.top_k tie-break).
__global__ void __launch_bounds__(256) k1_nms(const float* __restrict__ det,
                                              uint32_t* __restrict__ hdr,
                                              uint32_t* __restrict__ hist,
                                              uint64_t* __restrict__ keys) {
    __shared__ float sm[12][36];
    const int bx = blockIdx.x * 32, by = blockIdx.y * 8;
    const int tid = threadIdx.y * 32 + threadIdx.x;
    for (int k = tid; k < 12 * 36; k += 256) {
        int ly = k / 36, lx = k % 36;
        int gy = by + ly - 2, gx = bx + lx - 2;
        float v = -INFINITY;
        if ((unsigned)gy < H && (unsigned)gx < W) v = det[gy * W + gx];
        sm[ly][lx] = v;
    }
    __syncthreads();
    const int tx = threadIdx.x, ty = threadIdx.y;
    const float s = sm[ty + 2][tx + 2];
    float mx = -INFINITY;
#pragma unroll
    for (int dy = 0; dy < 5; ++dy)
#pragma unroll
        for (int dx = 0; dx < 5; ++dx) mx = fmaxf(mx, sm[ty + dy][tx + dx]);
    const int gx = bx + tx, gy = by + ty;
    const bool ok = (s == mx) && (s > 0.0f) && (gy >= 4) && (gy < H - 4) &&
                    (gx >= 4) && (gx < W - 4);
    if (ok) {
        uint32_t idx = (uint32_t)(gy * W + gx);
        uint32_t sb = __float_as_uint(s);
        uint64_t key = ((uint64_t)sb << 32) | (uint64_t)(0xFFFFFFFFu - idx);
        int bin = (int)(s * (float)NBINS);
        if (bin > NBINS - 1) bin = NBINS - 1;
        uint32_t slot = atomicAdd(&hdr[0], 1u);
        if (slot < CAND_CAP) {
            keys[slot] = key;
            atomicAdd(&hist[bin], 1u);
        }
    }
}

// K2: find threshold bin b* = max{b : count(bin >= b) >= TOPK} (single block).
__global__ void __launch_bounds__(256) k2_thresh(const uint32_t* __restrict__ hist,
                                                 uint32_t* __restrict__ hdr) {
    __shared__ uint32_t buf[256];
    __shared__ int lb[256];
    __shared__ uint32_t lm[256];
    __shared__ uint32_t s_tot;
    const int t = threadIdx.x;
    uint32_t sum = 0;
    for (int i = 0; i < 64; ++i) sum += hist[t * 64 + i];
    // inclusive suffix scan over 256 chunk sums (Hillis-Steele)
    uint32_t incl = sum;
    for (int d = 1; d < 256; d <<= 1) {
        buf[t] = incl;
        __syncthreads();
        uint32_t add = (t + d < 256) ? buf[t + d] : 0u;
        __syncthreads();
        incl += add;
    }
    if (t == 0) s_tot = incl;
    const uint32_t above = incl - sum;  // sum of all higher chunks
    int local_b = -1;
    uint32_t local_m = 0;
    uint32_t run = above;
    for (int i = 63; i >= 0; --i) {
        run += hist[t * 64 + i];
        if (run >= TOPK) {   // run == C(t*64+i), count of keys in bins >= t*64+i
            local_b = t * 64 + i;
            local_m = run;
            break;
        }
    }
    lb[t] = local_b;
    lm[t] = local_m;
    __syncthreads();
    for (int d = 128; d > 0; d >>= 1) {
        if (t < d) {
            if (lb[t + d] > lb[t]) { lb[t] = lb[t + d]; lm[t] = lm[t + d]; }
        }
        __syncthreads();
    }
    if (t == 0) {
        int b = lb[0];
        uint32_t m = lm[0];
        if (b < 0) { b = 0; m = s_tot; }  // fewer than TOPK candidates
        hdr[2] = (uint32_t)b;
        hdr[3] = m;
    }
}

// K3: compact keys whose score-bin >= b*.
__global__ void __launch_bounds__(256) k3_compact(const uint64_t* __restrict__ keys,
                                                  uint32_t* __restrict__ hdr,
                                                  uint64_t* __restrict__ compact) {
    uint32_t n = hdr[0];
    if (n > CAND_CAP) n = CAND_CAP;
    const uint32_t b = hdr[2];
    const uint32_t id = blockIdx.x * 256 + threadIdx.x;
    if (id >= n) return;
    const uint64_t key = keys[id];
    const float s = __uint_as_float((uint32_t)(key >> 32));
    int bin = (int)(s * (float)NBINS);   // identical expr to K1 -> same bits
    if (bin > NBINS - 1) bin = NBINS - 1;
    if ((uint32_t)bin >= b) {
        uint32_t pos = atomicAdd(&hdr[1], 1u);
        if (pos < COMPACT_CAP) compact[pos] = key;
    }
}

// K4: exact rank by counting greater keys (unique keys -> dense permutation).
// Writes kpts, scores, and sorted idx at position == rank. Deterministic
// regardless of the atomic-append order in K1/K3.
// LDS reads are paired (ulonglong2 / ds_read_b128) to halve the issue count
// on the single per-CU LDS pipe: 4 waves x ~4100 broadcast b64 reads was the
// modeled bottleneck (~98k cyc/CU); b128 pairs cut issues 2x.
__global__ void __launch_bounds__(256) k4_rank(const uint64_t* __restrict__ compact,
                                               const uint32_t* __restrict__ hdr,
                                               float* __restrict__ out,
                                               uint32_t* __restrict__ sidx) {
    __shared__ __align__(16) uint64_t lk[COMPACT_CAP];  // 64 KB
    uint32_t mc = hdr[1];
    if (mc > COMPACT_CAP) mc = COMPACT_CAP;
    for (uint32_t j = threadIdx.x; j < mc; j += 256) lk[j] = compact[j];
    __syncthreads();
    const uint32_t i = blockIdx.x * 256 + threadIdx.x;
    if (i >= mc) return;
    const uint64_t ki = lk[i];
    const ulonglong2* lk2 = (const ulonglong2*)lk;
    const uint32_t half = mc >> 1;
    uint32_t rank = 0;
    uint32_t j = 0;
    for (; j + 4 <= half; j += 4) {
#pragma unroll
        for (int u = 0; u < 4; ++u) {
            ulonglong2 p = lk2[j + u];
            rank += (p.x > ki) ? 1u : 0u;
            rank += (p.y > ki) ? 1u : 0u;
        }
    }
    for (; j < half; ++j) {
        ulonglong2 p = lk2[j];
        rank += (p.x > ki) ? 1u : 0u;
        rank += (p.y > ki) ? 1u : 0u;
    }
    if (mc & 1) rank += (lk[mc - 1] > ki) ? 1u : 0u;
    if (rank < TOPK) {
        const uint32_t idx = 0xFFFFFFFFu - (uint32_t)(ki & 0xFFFFFFFFull);
        const uint32_t y = idx >> 10, x = idx & 1023u;
        const float s = __uint_as_float((uint32_t)(ki >> 32));
        out[rank * 2 + 0] = (float)x;
        out[rank * 2 + 1] = (float)y;
        out[2 * TOPK + rank] = s;
        sidx[rank] = idx;
    }
}

// K5: descriptor gather. px,py are exactly integer keypoint coords (f32
// algebra is exact), so bilinear sampling reduces to a direct gather:
// descs[i][c] = desc[c][idx]. idx masked to HW-1 purely as OOB armor.
__global__ void __launch_bounds__(256) k5_desc(const float* __restrict__ desc,
                                               const uint32_t* __restrict__ sidx,
                                               float* __restrict__ out) {
    const uint32_t t = blockIdx.x * 256 + threadIdx.x;  // 0 .. TOPK*64-1
    const uint32_t i = t >> 6, c = t & 63u;
    const uint32_t idx = sidx[i] & (HW - 1);
    out[3 * TOPK + t] = desc[(size_t)c * HW + idx];
}

extern "C" void kernel_launch(void* const* d_in, const int* in_sizes, int n_in,
                              void* d_out, int out_size, void* d_ws, size_t ws_size,
                              hipStream_t stream) {
    const float* raw_desc = (const float*)d_in[0];
    const float* raw_detect = (const float*)d_in[1];
    float* out = (float*)d_out;
    uint8_t* ws = (uint8_t*)d_ws;
    uint32_t* hdr = (uint32_t*)ws;
    uint32_t* hist = (uint32_t*)(ws + OFF_HIST);
    uint64_t* keys = (uint64_t*)(ws + OFF_KEYS);
    uint64_t* compact = (uint64_t*)(ws + OFF_COMPACT);
    uint32_t* sidx = (uint32_t*)(ws + OFF_SIDX);

    hipMemsetAsync(ws, 0, OFF_HIST + NBINS * 4, stream);  // hdr + hist

    dim3 b1(32, 8);
    dim3 g1(W / 32, H / 8);
    k1_nms<<<g1, b1, 0, stream>>>(raw_detect, hdr, hist, keys);
    k2_thresh<<<1, 256, 0, stream>>>(hist, hdr);
    k3_compact<<<CAND_CAP / 256, 256, 0, stream>>>(keys, hdr, compact);
    k4_rank<<<COMPACT_CAP / 256, 256, 0, stream>>>(compact, hdr, out, sidx);
    k5_desc<<<TOPK * 64 / 256, 256, 0, stream>>>(raw_desc, sidx, out);
}

// Round 12
// 364.062 us; speedup vs baseline: 1.5598x; 1.5598x over previous
//
#include <hip/hip_runtime.h>
#include <stdint.h>

#define H 1024
#define W 1024
#define HW (H * W)
#define TOPK 4096
#define NBINS 16384
#define SORT_CAP 8192

// ---------------- ws layout (bytes) ----------------
// [0,256)        hdr: [2]=b_star [3]=mc
// [256,+64K)     hist[NBINS]      (memset 0)
// [+64K,+64K)    binoff[NBINS]    (memset 0)
// [+64K,+64K)    rank_base[NBINS] (fully written by K2)
// [..,+64K)      sorted keys [SORT_CAP]
// [..,+16K)      sidx [TOPK]
// total ~272 KB
#define OFF_HIST   256
#define OFF_BINOFF (OFF_HIST + NBINS * 4)
#define OFF_RANKB  (OFF_BINOFF + NBINS * 4)
#define OFF_SORT   (OFF_RANKB + NBINS * 4)
#define OFF_SIDX   (OFF_SORT + SORT_CAP * 8)
#define MEMSET_BYTES OFF_RANKB   // hdr + hist + binoff

// Shared 5x5-NMS tile machinery. fmax is associative+commutative, so K1 and
// K3 recomputing it produce bit-identical survivor sets.
__device__ __forceinline__ void load_tile(const float* __restrict__ det,
                                          float sm[12][36], int bx, int by,
                                          int tid) {
    for (int k = tid; k < 12 * 36; k += 256) {
        int ly = k / 36, lx = k % 36;
        int gy = by + ly - 2, gx = bx + lx - 2;
        float v = -INFINITY;
        if ((unsigned)gy < H && (unsigned)gx < W) v = det[gy * W + gx];
        sm[ly][lx] = v;
    }
}

__device__ __forceinline__ bool nms_ok(const float sm[12][36], int tx, int ty,
                                       int gx, int gy, float& s_out) {
    const float s = sm[ty + 2][tx + 2];
    float mx = -INFINITY;
#pragma unroll
    for (int dy = 0; dy < 5; ++dy)
#pragma unroll
        for (int dx = 0; dx < 5; ++dx) mx = fmaxf(mx, sm[ty + dy][tx + dx]);
    s_out = s;
    return (s == mx) && (s > 0.0f) && (gy >= 4) && (gy < H - 4) && (gx >= 4) &&
           (gx < W - 4);
}

__device__ __forceinline__ int score_bin(float s) {
    int bin = (int)(s * (float)NBINS);
    return (bin > NBINS - 1) ? (NBINS - 1) : bin;
}

// K1: NMS pass 1 — scattered histogram only. NO single-line counters
// (the 180us baseline was serialization on atomicAdd(&hdr[0]) — 1 line,
// ~16k wave-atomics x ~27cyc across 8 XCDs).
__global__ void __launch_bounds__(256) k1_nms(const float* __restrict__ det,
                                              uint32_t* __restrict__ hist) {
    __shared__ float sm[12][36];
    const int bx = blockIdx.x * 32, by = blockIdx.y * 8;
    const int tid = threadIdx.y * 32 + threadIdx.x;
    load_tile(det, sm, bx, by, tid);
    __syncthreads();
    const int tx = threadIdx.x, ty = threadIdx.y;
    const int gx = bx + tx, gy = by + ty;
    float s;
    if (nms_ok(sm, tx, ty, gx, gy, s)) {
        atomicAdd(&hist[score_bin(s)], 1u);  // ~41k ops over 1024 lines
    }
}

// K2: single block. Computes, for every bin, rank_base[b] = #keys in bins > b
// (exact suffix sums), plus b* = max{b : C(b) >= TOPK} and mc = C(b*).
__global__ void __launch_bounds__(256) k2_thresh(const uint32_t* __restrict__ hist,
                                                 uint32_t* __restrict__ hdr,
                                                 uint32_t* __restrict__ rank_base) {
    __shared__ uint32_t buf[256];
    __shared__ int lb[256];
    __shared__ uint32_t lm[256];
    const int t = threadIdx.x;
    uint32_t sum = 0;
    for (int i = 0; i < 64; ++i) sum += hist[t * 64 + i];
    // inclusive suffix scan of chunk sums (Hillis-Steele)
    uint32_t incl = sum;
    for (int d = 1; d < 256; d <<= 1) {
        buf[t] = incl;
        __syncthreads();
        uint32_t add = (t + d < 256) ? buf[t + d] : 0u;
        __syncthreads();
        incl += add;
    }
    const uint32_t above = incl - sum;  // total keys in higher chunks
    int local_b = -1;
    uint32_t local_m = 0;
    uint32_t run = above;
    for (int i = 63; i >= 0; --i) {
        const int b = t * 64 + i;
        rank_base[b] = run;         // C(b+1): keys strictly above bin b
        run += hist[b];             // now run == C(b)
        if (local_b < 0 && run >= TOPK) { local_b = b; local_m = run; }
    }
    lb[t] = local_b;
    lm[t] = local_m;
    __syncthreads();
    for (int d = 128; d > 0; d >>= 1) {
        if (t < d) {
            if (lb[t + d] > lb[t]) { lb[t] = lb[t + d]; lm[t] = lm[t + d]; }
        }
        __syncthreads();
    }
    if (t == 0) {
        int b = lb[0];
        uint32_t m = lm[0];
        if (b < 0) { b = 0; m = run; }  // degenerate: fewer than TOPK keys
        hdr[2] = (uint32_t)b;
        hdr[3] = m;                     // mc = C(b*) = #keys scattered by K3
    }
}

// K3: NMS pass 2 (detect map is L2-resident) — scatter survivors with
// bin >= b* into their bin segment. Atomics are spread over ~100+ lines.
// key = (score_bits<<32) | (0xFFFFFFFF - idx): order matches lax.top_k
// (score desc, ties -> lower flat index).
__global__ void __launch_bounds__(256) k3_scatter(const float* __restrict__ det,
                                                  const uint32_t* __restrict__ hdr,
                                                  const uint32_t* __restrict__ rank_base,
                                                  uint32_t* __restrict__ binoff,
                                                  uint64_t* __restrict__ sorted) {
    __shared__ float sm[12][36];
    const int bx = blockIdx.x * 32, by = blockIdx.y * 8;
    const int tid = threadIdx.y * 32 + threadIdx.x;
    load_tile(det, sm, bx, by, tid);
    __syncthreads();
    const int tx = threadIdx.x, ty = threadIdx.y;
    const int gx = bx + tx, gy = by + ty;
    float s;
    if (nms_ok(sm, tx, ty, gx, gy, s)) {
        const int bin = score_bin(s);
        const uint32_t bstar = hdr[2];
        if ((uint32_t)bin >= bstar) {
            const uint32_t idx = (uint32_t)(gy * W + gx);
            const uint64_t key =
                ((uint64_t)__float_as_uint(s) << 32) | (uint64_t)(0xFFFFFFFFu - idx);
            const uint32_t pos = rank_base[bin] + atomicAdd(&binoff[bin], 1u);
            if (pos < SORT_CAP) sorted[pos] = key;
        }
    }
}

// K4: exact rank = rank_base[bin] + (#greater keys within own bin segment).
// Segment length = hist[bin], avg ~2.5. Unique keys -> ranks are a dense
// permutation; writes are deterministic regardless of scatter order.
__global__ void __launch_bounds__(256) k4_final(const uint64_t* __restrict__ sorted,
                                                const uint32_t* __restrict__ hist,
                                                const uint32_t* __restrict__ rank_base,
                                                const uint32_t* __restrict__ hdr,
                                                float* __restrict__ out,
                                                uint32_t* __restrict__ sidx) {
    uint32_t mc = hdr[3];
    if (mc > SORT_CAP) mc = SORT_CAP;
    const uint32_t si = blockIdx.x * 256 + threadIdx.x;
    if (si >= mc) return;
    const uint64_t key = sorted[si];
    const float sc = __uint_as_float((uint32_t)(key >> 32));
    const int bin = score_bin(sc);
    const uint32_t base = rank_base[bin];
    const uint32_t len = hist[bin];
    uint32_t r = 0;
    for (uint32_t j = 0; j < len; ++j) r += (sorted[base + j] > key) ? 1u : 0u;
    const uint32_t rank = base + r;
    if (rank < TOPK) {
        const uint32_t idx = 0xFFFFFFFFu - (uint32_t)(key & 0xFFFFFFFFull);
        const uint32_t y = idx >> 10, x = idx & 1023u;
        out[rank * 2 + 0] = (float)x;
        out[rank * 2 + 1] = (float)y;
        out[2 * TOPK + rank] = sc;
        sidx[rank] = idx;
    }
}

// K5: descriptor gather. The reference's grid_sample coords reduce exactly
// to integer pixel coords in f32, so descs[i][c] = desc[c][idx]. Mask is
// OOB armor only.
__global__ void __launch_bounds__(256) k5_desc(const float* __restrict__ desc,
                                               const uint32_t* __restrict__ sidx,
                                               float* __restrict__ out) {
    const uint32_t t = blockIdx.x * 256 + threadIdx.x;  // 0 .. TOPK*64-1
    const uint32_t i = t >> 6, c = t & 63u;
    const uint32_t idx = sidx[i] & (HW - 1);
    out[3 * TOPK + t] = desc[(size_t)c * HW + idx];
}

extern "C" void kernel_launch(void* const* d_in, const int* in_sizes, int n_in,
                              void* d_out, int out_size, void* d_ws, size_t ws_size,
                              hipStream_t stream) {
    const float* raw_desc = (const float*)d_in[0];
    const float* raw_detect = (const float*)d_in[1];
    float* out = (float*)d_out;
    uint8_t* ws = (uint8_t*)d_ws;
    uint32_t* hdr = (uint32_t*)ws;
    uint32_t* hist = (uint32_t*)(ws + OFF_HIST);
    uint32_t* binoff = (uint32_t*)(ws + OFF_BINOFF);
    uint32_t* rank_base = (uint32_t*)(ws + OFF_RANKB);
    uint64_t* sorted = (uint64_t*)(ws + OFF_SORT);
    uint32_t* sidx = (uint32_t*)(ws + OFF_SIDX);

    hipMemsetAsync(ws, 0, MEMSET_BYTES, stream);  // hdr + hist + binoff

    dim3 b1(32, 8);
    dim3 g1(W / 32, H / 8);
    k1_nms<<<g1, b1, 0, stream>>>(raw_detect, hist);
    k2_thresh<<<1, 256, 0, stream>>>(hist, hdr, rank_base);
    k3_scatter<<<g1, b1, 0, stream>>>(raw_detect, hdr, rank_base, binoff, sorted);
    k4_final<<<SORT_CAP / 256, 256, 0, stream>>>(sorted, hist, rank_base, hdr, out, sidx);
    k5_desc<<<TOPK * 64 / 256, 256, 0, stream>>>(raw_desc, sidx, out);
}

// Round 13
// 361.388 us; speedup vs baseline: 1.5714x; 1.0074x over previous
//
#include <hip/hip_runtime.h>
#include <stdint.h>

#define H 1024
#define W 1024
#define HW (H * W)
#define TOPK 4096
#define NBINS 16384
#define SORT_CAP 65536
#define STAGE_SLOTS 64   // >= max survivors per 32x8 tile (theory: <=33)

// ---------------- ws layout (bytes) ----------------
// [0,256)          hdr: [3]=total survivor count
// [256,+64K)       hist[NBINS]        (memset 0)
// [65792,+64K)     binoff[NBINS]      (memset 0)
// [131328,+64K)    rank_base[NBINS]   (fully written by K2)
// [196864,+16K)    cnt[4096]          (fully written by K1)
// [213248,+2M)     stage[4096*64] u64 (written by K1 up to cnt)
// [2310400,+512K)  sorted[SORT_CAP] u64
// [2834688,+16K)   sidx[TOPK]
#define OFF_HIST   256
#define OFF_BINOFF (OFF_HIST + NBINS * 4)
#define OFF_RANKB  (OFF_BINOFF + NBINS * 4)
#define OFF_CNT    (OFF_RANKB + NBINS * 4)
#define OFF_STAGE  (OFF_CNT + 4096 * 4)
#define OFF_SORT   (OFF_STAGE + 4096 * STAGE_SLOTS * 8)
#define OFF_SIDX   (OFF_SORT + SORT_CAP * 8)
#define MEMSET_BYTES OFF_RANKB   // hdr + hist + binoff

__device__ __forceinline__ void load_tile(const float* __restrict__ det,
                                          float sm[12][36], int bx, int by,
                                          int tid) {
    for (int k = tid; k < 12 * 36; k += 256) {
        int ly = k / 36, lx = k % 36;
        int gy = by + ly - 2, gx = bx + lx - 2;
        float v = -INFINITY;
        if ((unsigned)gy < H && (unsigned)gx < W) v = det[gy * W + gx];
        sm[ly][lx] = v;
    }
}

__device__ __forceinline__ bool nms_ok(const float sm[12][36], int tx, int ty,
                                       int gx, int gy, float& s_out) {
    const float s = sm[ty + 2][tx + 2];
    float mx = -INFINITY;
#pragma unroll
    for (int dy = 0; dy < 5; ++dy)
#pragma unroll
        for (int dx = 0; dx < 5; ++dx) mx = fmaxf(mx, sm[ty + dy][tx + dx]);
    s_out = s;
    return (s == mx) && (s > 0.0f) && (gy >= 4) && (gy < H - 4) && (gx >= 4) &&
           (gx < W - 4);
}

__device__ __forceinline__ int score_bin(float s) {
    int bin = (int)(s * (float)NBINS);
    return (bin > NBINS - 1) ? (NBINS - 1) : bin;
}

// K1: single NMS pass. Histogram (scattered atomics, proven benign in r12)
// + per-block survivor staging so K3 never re-reads the detect map.
// key = (score_bits<<32) | (0xFFFFFFFF - idx): order == lax.top_k order.
__global__ void __launch_bounds__(256) k1_nms(const float* __restrict__ det,
                                              uint32_t* __restrict__ hist,
                                              uint64_t* __restrict__ stage,
                                              uint32_t* __restrict__ cnt) {
    __shared__ float sm[12][36];
    __shared__ uint32_t lds_cnt;
    const int bx = blockIdx.x * 32, by = blockIdx.y * 8;
    const int tid = threadIdx.y * 32 + threadIdx.x;
    if (tid == 0) lds_cnt = 0;
    load_tile(det, sm, bx, by, tid);
    __syncthreads();
    const int tx = threadIdx.x, ty = threadIdx.y;
    const int gx = bx + tx, gy = by + ty;
    const uint32_t b = blockIdx.y * gridDim.x + blockIdx.x;
    float s;
    if (nms_ok(sm, tx, ty, gx, gy, s)) {
        atomicAdd(&hist[score_bin(s)], 1u);
        const uint32_t idx = (uint32_t)(gy * W + gx);
        const uint64_t key =
            ((uint64_t)__float_as_uint(s) << 32) | (uint64_t)(0xFFFFFFFFu - idx);
        const uint32_t slot = atomicAdd(&lds_cnt, 1u);
        if (slot < STAGE_SLOTS) stage[b * STAGE_SLOTS + slot] = key;
    }
    __syncthreads();
    if (tid == 0) cnt[b] = lds_cnt < STAGE_SLOTS ? lds_cnt : STAGE_SLOTS;
}

// K2: pure suffix scan. rank_base[b] = #keys in bins > b, for ALL bins.
// hdr[3] = total survivors. (Threshold search removed: K4's rank<TOPK
// filter does the selection; scattering all ~41k keys costs ~0.3MB.)
__global__ void __launch_bounds__(256) k2_scan(const uint32_t* __restrict__ hist,
                                               uint32_t* __restrict__ hdr,
                                               uint32_t* __restrict__ rank_base) {
    __shared__ uint32_t buf[256];
    const int t = threadIdx.x;
    uint32_t sum = 0;
    for (int i = 0; i < 64; ++i) sum += hist[t * 64 + i];
    // inclusive suffix scan of 256 chunk sums (Hillis-Steele)
    uint32_t incl = sum;
    for (int d = 1; d < 256; d <<= 1) {
        buf[t] = incl;
        __syncthreads();
        uint32_t add = (t + d < 256) ? buf[t + d] : 0u;
        __syncthreads();
        incl += add;
    }
    uint32_t run = incl - sum;      // keys in all higher chunks
    for (int i = 63; i >= 0; --i) {
        const int b = t * 64 + i;
        rank_base[b] = run;         // keys strictly above bin b
        run += hist[b];
    }
    if (t == 0) hdr[3] = run;       // t==0: run == C(0) == total survivors
}

// K3: scatter staged keys into bin segments. Reads 0.3MB of staged keys
// instead of re-reading 6MB detect + redoing NMS (round-12 design).
__global__ void __launch_bounds__(64) k3_scatter(const uint64_t* __restrict__ stage,
                                                 const uint32_t* __restrict__ cnt,
                                                 const uint32_t* __restrict__ rank_base,
                                                 uint32_t* __restrict__ binoff,
                                                 uint64_t* __restrict__ sorted) {
    const uint32_t b = blockIdx.x;
    const uint32_t j = threadIdx.x;
    if (j < cnt[b]) {
        const uint64_t key = stage[b * STAGE_SLOTS + j];
        const float sc = __uint_as_float((uint32_t)(key >> 32));
        const int bin = score_bin(sc);
        const uint32_t pos = rank_base[bin] + atomicAdd(&binoff[bin], 1u);
        if (pos < SORT_CAP) sorted[pos] = key;
    }
}

// K4: exact rank = rank_base[bin] + #greater within own bin segment
// (segment avg ~2.5 keys). Unique keys -> dense permutation; writes are
// deterministic regardless of scatter order. Only ranks < TOPK emit.
__global__ void __launch_bounds__(256) k4_final(const uint64_t* __restrict__ sorted,
                                                const uint32_t* __restrict__ hist,
                                                const uint32_t* __restrict__ rank_base,
                                                const uint32_t* __restrict__ hdr,
                                                float* __restrict__ out,
                                                uint32_t* __restrict__ sidx) {
    uint32_t mc = hdr[3];
    if (mc > SORT_CAP) mc = SORT_CAP;
    const uint32_t si = blockIdx.x * 256 + threadIdx.x;
    if (si >= mc) return;
    const uint64_t key = sorted[si];
    const float sc = __uint_as_float((uint32_t)(key >> 32));
    const int bin = score_bin(sc);
    const uint32_t base = rank_base[bin];
    const uint32_t len = hist[bin];
    uint32_t r = 0;
    for (uint32_t j = 0; j < len; ++j) r += (sorted[base + j] > key) ? 1u : 0u;
    const uint32_t rank = base + r;
    if (rank < TOPK) {
        const uint32_t idx = 0xFFFFFFFFu - (uint32_t)(key & 0xFFFFFFFFull);
        const uint32_t y = idx >> 10, x = idx & 1023u;
        out[rank * 2 + 0] = (float)x;
        out[rank * 2 + 1] = (float)y;
        out[2 * TOPK + rank] = sc;
        sidx[rank] = idx;
    }
}

// K5: descriptor gather. grid_sample coords reduce exactly to integer pixel
// coords in f32 -> descs[i][c] = desc[c][idx]. One wave per keypoint,
// lanes = channels; writes fully coalesced. Mask is OOB armor only.
__global__ void __launch_bounds__(256) k5_desc(const float* __restrict__ desc,
                                               const uint32_t* __restrict__ sidx,
                                               float* __restrict__ out) {
    const uint32_t t = blockIdx.x * 256 + threadIdx.x;  // 0 .. TOPK*64-1
    const uint32_t i = t >> 6, c = t & 63u;
    const uint32_t idx = sidx[i] & (HW - 1);
    out[3 * TOPK + t] = desc[(size_t)c * HW + idx];
}

extern "C" void kernel_launch(void* const* d_in, const int* in_sizes, int n_in,
                              void* d_out, int out_size, void* d_ws, size_t ws_size,
                              hipStream_t stream) {
    const float* raw_desc = (const float*)d_in[0];
    const float* raw_detect = (const float*)d_in[1];
    float* out = (float*)d_out;
    uint8_t* ws = (uint8_t*)d_ws;
    uint32_t* hdr = (uint32_t*)ws;
    uint32_t* hist = (uint32_t*)(ws + OFF_HIST);
    uint32_t* binoff = (uint32_t*)(ws + OFF_BINOFF);
    uint32_t* rank_base = (uint32_t*)(ws + OFF_RANKB);
    uint32_t* cnt = (uint32_t*)(ws + OFF_CNT);
    uint64_t* stage = (uint64_t*)(ws + OFF_STAGE);
    uint64_t* sorted = (uint64_t*)(ws + OFF_SORT);
    uint32_t* sidx = (uint32_t*)(ws + OFF_SIDX);

    hipMemsetAsync(ws, 0, MEMSET_BYTES, stream);  // hdr + hist + binoff

    dim3 b1(32, 8);
    dim3 g1(W / 32, H / 8);
    k1_nms<<<g1, b1, 0, stream>>>(raw_detect, hist, stage, cnt);
    k2_scan<<<1, 256, 0, stream>>>(hist, hdr, rank_base);
    k3_scatter<<<4096, 64, 0, stream>>>(stage, cnt, rank_base, binoff, sorted);
    k4_final<<<SORT_CAP / 256, 256, 0, stream>>>(sorted, hist, rank_base, hdr, out, sidx);
    k5_desc<<<TOPK * 64 / 256, 256, 0, stream>>>(raw_desc, sidx, out);
}